// Round 3
// baseline (370.414 us; speedup 1.0000x reference)
//
#include <hip/hip_runtime.h>
#include <math.h>

typedef _Float16 half_t;
typedef __attribute__((ext_vector_type(4))) _Float16 half4v;
typedef __attribute__((ext_vector_type(8))) _Float16 half8v;
typedef __attribute__((ext_vector_type(4))) float floatx4;

constexpr int B_ = 4, S_ = 4096, D_ = 2048, H_ = 1024, H2_ = 512, E_ = 8;
constexpr int CHUNK_ = 128;
constexpr int C_ = S_ / CHUNK_;          // 32
constexpr int M_ = B_ * S_;              // 16384
constexpr float TAU_ = 0.7f;
// Precision ledger (measured): full split absmax=0 (R2); x/W1 pure-f16 +
// W2 split kept -> absmax = 2^-9 (R4-R6), 60x under threshold. W2 residual
// kept: h1>=0 (positive mean) makes W2-rounding coherent through the chunk
// mean; x/W1 rounding is token-incoherent -> averages out ~sqrt(128).
constexpr float WSCALE = 64.0f, OSCALE = 1.0f / 64.0f;

constexpr int OUT_RW = 0;
constexpr int OUT_EI = OUT_RW + B_ * S_ * E_;
constexpr int OUT_CL = OUT_EI + B_ * C_;
constexpr int OUT_GE = OUT_CL + B_ * C_ * E_;
constexpr int OUT_UT = OUT_GE + 1;
constexpr int OUT_FR = OUT_UT + E_;
constexpr int OUT_RC = OUT_FR + 1;

// ---------------------------------------------------------------------------
// Prep (one launch):
//   blocks [0,8192):       x fp32 -> f16 (1024 float4 per block)
//   blocks [8192,10240):   w1 [D,H] -> w1t [H,D] f16
//   blocks [10240,10752):  w2 [H,H2] -> w2t hi/lo [H2,H], pre-scaled x64
//   block  10752:          zero cl_acc
// ---------------------------------------------------------------------------
__global__ __launch_bounds__(256)
void prep_kernel(const float* __restrict__ x, const float* __restrict__ w1,
                 const float* __restrict__ w2,
                 half_t* __restrict__ xh, half_t* __restrict__ w1t,
                 half_t* __restrict__ w2th, half_t* __restrict__ w2tl,
                 float* __restrict__ cl_acc)
{
    __shared__ float tile[32][33];
    const int tx = threadIdx.x & 31;
    const int ty = threadIdx.x >> 5;
    const int bid = blockIdx.x;

    if (bid < 8192) {                     // convert x: 1024 float4 per block
        const int base = bid * 1024 + threadIdx.x;
#pragma unroll
        for (int p = 0; p < 4; ++p) {
            const int i = base + p * 256;
            const float4 v = ((const float4*)x)[i];
            half4v h;
            h.x = (half_t)v.x; h.y = (half_t)v.y; h.z = (half_t)v.z; h.w = (half_t)v.w;
            ((half4v*)xh)[i] = h;
        }
    } else if (bid < 10240) {             // w1 transpose -> f16
        const int b2 = bid - 8192;
        const int n0 = (b2 & 31) * 32;    // H_/32 = 32
        const int k0 = (b2 >> 5) * 32;    // D_/32 = 64
#pragma unroll
        for (int r = 0; r < 4; ++r)
            tile[ty + r * 8][tx] = w1[(size_t)(k0 + ty + r * 8) * H_ + n0 + tx];
        __syncthreads();
#pragma unroll
        for (int r = 0; r < 4; ++r)
            w1t[(size_t)(n0 + ty + r * 8) * D_ + k0 + tx] = (half_t)tile[tx][ty + r * 8];
    } else if (bid < 10752) {             // w2 transpose + split
        const int b2 = bid - 10240;
        const int n0 = (b2 & 15) * 32;    // H2_/32 = 16
        const int k0 = (b2 >> 4) * 32;    // H_/32 = 32
#pragma unroll
        for (int r = 0; r < 4; ++r)
            tile[ty + r * 8][tx] = w2[(size_t)(k0 + ty + r * 8) * H2_ + n0 + tx];
        __syncthreads();
#pragma unroll
        for (int r = 0; r < 4; ++r) {
            const float v = tile[tx][ty + r * 8] * WSCALE;
            const half_t h = (half_t)v;
            const size_t off = (size_t)(n0 + ty + r * 8) * H_ + k0 + tx;
            w2th[off] = h;
            w2tl[off] = (half_t)(v - (float)h);
        }
    } else {                              // zero chunk-logit accumulator
        for (int i = threadIdx.x; i < B_ * C_ * E_; i += 256) cl_acc[i] = 0.0f;
    }
}

// ---------------------------------------------------------------------------
// GEMM1: h1 = relu(xh @ w1 + b1) -> f16.
// R7: 256x256x(BK=64) 8-phase counted-vmcnt schedule (learn_hip m201 port).
// R8: paired-row LDS layout -> bank conflicts = 0 (verified by PMC).
// R9: cross-phase register double-buffer. R8 was phase-serial: reads(576cy)
//   then MFMA(621cy) with nothing overlapped (1556 cy/phase measured). Now
//   each phase issues the NEXT phase's ds_reads into the alternate fragment
//   set, waits lgkmcnt(N_just_issued) (drains only the PREVIOUS phase's
//   reads), and MFMAs the current set while LDS processes the new reads.
//   One barrier per phase. Hazard ledger:
//   - WAR restage-vs-read: every slot's restage = last-read-issue-phase + 2
//     (lgkm drain at +1, barrier, restage at +2). Verified all 4 slots.
//   - RAW stage-landing-vs-read: per-wave vmcnt must be followed by a
//     BARRIER before dependent reads (staging is cooperative). vmcnt(8) at
//     P1-tail covers tile-t h1 (reads @P2,P3); vmcnt(8) at P3-tail covers
//     tile-(t+1) h0 (reads @P4). Boundary: vmcnt(0)@P1(NT-1),
//     vmcnt(4)@P3(NT-2). Counts exact vs unchanged stage schedule.
//   - frag reg WAR: write slot = read slot of 2 phases prior. All indices
//     compile-time (rule #20); sched_barrier(0) after lgkm (rule #18).
//   K-accumulation order identical -> bitwise-identical C (absmax canary).
// ---------------------------------------------------------------------------
__device__ __forceinline__ int lds_off_g(int row, int q)
{
    // half-index into a k-half tile for (row, k-quarter q)
    const int line = row >> 1;
    const int sl = (((row & 1) << 2) | q) ^ (line & 7);
    return line * 64 + sl * 8;
}

__device__ __forceinline__ void stage_half_g1(const half_t* __restrict__ g,
                                              half_t* l, int tid)
{
    // LDS[line][s] <- global(row = 2*line + p, k = q*8) with p*4+q = s^(line&7)
    const int s = tid & 7;
#pragma unroll
    for (int r = 0; r < 2; ++r) {
        const int line = r * 64 + (tid >> 3);
        const int u = s ^ (line & 7);
        const int row = line * 2 + (u >> 2);
        const int kq = (u & 3) * 8;
        __builtin_amdgcn_global_load_lds(
            (const __attribute__((address_space(1))) void*)(g + (size_t)row * D_ + kq),
            (__attribute__((address_space(3))) void*)(l + (r * 512 + tid) * 8),
            16, 0, 0);
    }
}

__global__ __launch_bounds__(512, 2)
void gemm1_kernel(const half_t* __restrict__ Ah,
                  const half_t* __restrict__ BTh,
                  const float* __restrict__ bias, half_t* __restrict__ outh)
{
    constexpr int KD = D_;        // 2048
    constexpr int ND = H_;        // 1024
    constexpr int NT = KD / 64;   // 32 K-tiles

    __shared__ __align__(16) half_t sA[2][2][256 * 32];   // [dbuf][khalf]
    __shared__ __align__(16) half_t sB[2][2][256 * 32];

    const int tid = threadIdx.x;
    const int lane = tid & 63;
    const int wave = tid >> 6;
    const int wRow = (wave >> 2) * 128;     // 2 M-wave-groups
    const int wCol = (wave & 3) * 64;       // 4 N-wave-groups
    const int fr = lane & 15;
    const int q = lane >> 4;                // k-quarter

    // XCD-bijective swizzle: bid%8 = XCD; each XCD owns a contiguous
    // 8-M-block stripe x all 4 N-blocks (B panels + A rows L2-local).
    const int bid = blockIdx.x;
    const long blockM = (long)((bid & 7) * 8 + (bid >> 5)) * 256;
    const long blockN = (long)((bid >> 3) & 3) * 256;

    const half_t* gA = Ah + (size_t)blockM * KD;
    const half_t* gB = BTh + (size_t)blockN * KD;

    floatx4 acc[8][4];
#pragma unroll
    for (int i = 0; i < 8; ++i)
#pragma unroll
        for (int j = 0; j < 4; ++j) acc[i][j] = (floatx4){0.f, 0.f, 0.f, 0.f};

    // Fragment double-buffers: afr2 alternates per phase; bfr2 per k-half.
    half8v afr2[2][4];
    half8v bfr2[2][4];

#define G1_VM(N)   asm volatile("s_waitcnt vmcnt(" #N ")" ::: "memory")
#define G1_LGKM(N) asm volatile("s_waitcnt lgkmcnt(" #N ")" ::: "memory")

#define RD_A(BUFi, Hi, MBv, SL)                                                \
    do {                                                                       \
        afr2[SL][0] = *(const half8v*)(sA[BUFi][Hi] + lds_off_g(wRow + (MBv) + 0 + fr, q));  \
        afr2[SL][1] = *(const half8v*)(sA[BUFi][Hi] + lds_off_g(wRow + (MBv) + 16 + fr, q)); \
        afr2[SL][2] = *(const half8v*)(sA[BUFi][Hi] + lds_off_g(wRow + (MBv) + 32 + fr, q)); \
        afr2[SL][3] = *(const half8v*)(sA[BUFi][Hi] + lds_off_g(wRow + (MBv) + 48 + fr, q)); \
    } while (0)
#define RD_B(BUFi, Hi, SL)                                                     \
    do {                                                                       \
        bfr2[SL][0] = *(const half8v*)(sB[BUFi][Hi] + lds_off_g(wCol + 0 + fr, q));  \
        bfr2[SL][1] = *(const half8v*)(sB[BUFi][Hi] + lds_off_g(wCol + 16 + fr, q)); \
        bfr2[SL][2] = *(const half8v*)(sB[BUFi][Hi] + lds_off_g(wCol + 32 + fr, q)); \
        bfr2[SL][3] = *(const half8v*)(sB[BUFi][Hi] + lds_off_g(wCol + 48 + fr, q)); \
    } while (0)

    // Prologue: tile0 complete + steady-state 3 halves of tile1 in flight,
    // then the reads for P1(0). vmcnt(10) guarantees tile0.h0 (first 2
    // halves staged) landed; barrier makes it block-wide before the reads.
    stage_half_g1(gA,      sA[0][0], tid);   // A0.h0
    stage_half_g1(gB,      sB[0][0], tid);   // B0.h0
    stage_half_g1(gA + 32, sA[0][1], tid);   // A0.h1
    stage_half_g1(gB + 32, sB[0][1], tid);   // B0.h1
    stage_half_g1(gB + 64, sB[1][0], tid);   // B1.h0   (as-if (t-1,P2))
    stage_half_g1(gA + 64, sA[1][0], tid);   // A1.h0   (as-if (t-1,P3))
    stage_half_g1(gB + 96, sB[1][1], tid);   // B1.h1   (as-if (t-1,P4))
    G1_VM(10);
    __builtin_amdgcn_s_barrier();
    __builtin_amdgcn_sched_barrier(0);
    RD_B(0, 0, 0);          // bfr for P1/P2 of tile0
    RD_A(0, 0, 0, 0);       // afr for P1 of tile0 (MB=0)

#define G1_PHASE(RD_STMT, STAGE_STMT, LGKM_STMT, FA, FB, MBv, TAIL_STMT)       \
    {                                                                          \
        RD_STMT;                                                               \
        STAGE_STMT;                                                            \
        LGKM_STMT;                                                             \
        __builtin_amdgcn_sched_barrier(0);                                     \
        __builtin_amdgcn_s_setprio(1);                                         \
        _Pragma("unroll")                                                      \
        for (int m = 0; m < 4; ++m)                                            \
            _Pragma("unroll")                                                  \
            for (int n = 0; n < 4; ++n)                                        \
                acc[(MBv) / 16 + m][n] = __builtin_amdgcn_mfma_f32_16x16x32_f16(\
                    afr2[FA][m], bfr2[FB][n], acc[(MBv) / 16 + m][n], 0, 0, 0);\
        __builtin_amdgcn_s_setprio(0);                                         \
        TAIL_STMT;                                                             \
        __builtin_amdgcn_s_barrier();                                          \
        __builtin_amdgcn_sched_barrier(0);                                     \
    }

#define G1_TILE(BUF, T)                                                        \
    {                                                                          \
        /* P1: MFMA(h0,MB0); reads->P2 (afr MB64); stage A(t+1).h1 */          \
        G1_PHASE(RD_A(BUF, 0, 64, 1),                                          \
            if ((T) + 1 < NT) stage_half_g1(gA + ((T) + 1) * 64 + 32,          \
                                            sA[(BUF) ^ 1][1], tid),            \
            G1_LGKM(4), 0, 0, 0,                                               \
            if ((T) < NT - 1) { G1_VM(8); } else { G1_VM(0); });               \
        /* P2: MFMA(h0,MB64); reads->P3 (bfr h1 + afr MB0); stage B(t+2).h0 */ \
        G1_PHASE(RD_B(BUF, 1, 1); RD_A(BUF, 1, 0, 0),                          \
            if ((T) + 2 < NT) stage_half_g1(gB + ((T) + 2) * 64,               \
                                            sB[(BUF)][0], tid),                \
            G1_LGKM(8), 1, 0, 64, );                                           \
        /* P3: MFMA(h1,MB0); reads->P4 (afr MB64); stage A(t+2).h0 */          \
        G1_PHASE(RD_A(BUF, 1, 64, 1),                                          \
            if ((T) + 2 < NT) stage_half_g1(gA + ((T) + 2) * 64,               \
                                            sA[(BUF)][0], tid),                \
            G1_LGKM(4), 0, 1, 0,                                               \
            if ((T) < NT - 2) { G1_VM(8); } else if ((T) == NT - 2) { G1_VM(4); }); \
        /* P4: MFMA(h1,MB64); reads->P1(t+1) (bfr+afr h0); stage B(t+2).h1 */  \
        G1_PHASE(if ((T) < NT - 1) { RD_B((BUF) ^ 1, 0, 0); RD_A((BUF) ^ 1, 0, 0, 0); }, \
            if ((T) + 2 < NT) stage_half_g1(gB + ((T) + 2) * 64 + 32,          \
                                            sB[(BUF)][1], tid),                \
            if ((T) < NT - 1) { G1_LGKM(8); } else { G1_LGKM(0); },            \
            1, 1, 64, );                                                       \
    }

    for (int t = 0; t < NT; t += 2) {
        G1_TILE(0, t);
        G1_TILE(1, t + 1);
    }
#undef G1_TILE
#undef G1_PHASE
#undef RD_A
#undef RD_B
#undef G1_VM
#undef G1_LGKM

    // Epilogue: relu(acc + bias) -> f16 store (same C/D mapping as before)
    const int orow = (lane >> 4) * 4;
    const int ocol = lane & 15;
#pragma unroll
    for (int n = 0; n < 4; ++n) {
        const long gn = blockN + wCol + n * 16 + ocol;
        const float bj = bias[gn];
#pragma unroll
        for (int m = 0; m < 8; ++m) {
#pragma unroll
            for (int r = 0; r < 4; ++r) {
                const float v = fmaxf(acc[m][n][r] + bj, 0.0f);
                outh[(size_t)(blockM + wRow + m * 16 + orow + r) * ND + gn] = (half_t)v;
            }
        }
    }
}

// ---------------------------------------------------------------------------
// GEMM2 fused: relu(h1 @ w2 + b2) @ w3, chunk-summed into cl_acc via
// device-scope atomics. h2 never materialized. f16x2 (W2 split kept).
// ---------------------------------------------------------------------------
__global__ __launch_bounds__(256, 3)
void gemm2_fused_kernel(const half_t* __restrict__ Ah,
                        const half_t* __restrict__ BTh, const half_t* __restrict__ BTl,
                        const float* __restrict__ bias, const float* __restrict__ w3,
                        float* __restrict__ cl_acc)
{
    constexpr int KD = H_, BK = 32;
    __shared__ __align__(16) half_t sAh[128 * BK];
    __shared__ __align__(16) half_t sBh[128 * BK];
    __shared__ __align__(16) half_t sBl[128 * BK];

    const int tid = threadIdx.x;
    const int lane = tid & 63;
    const int wave = tid >> 6;
    const int wm = (wave & 1) * 64;
    const int wn = (wave >> 1) * 64;
    const int d = blockIdx.y * 4 + blockIdx.x;
    const int xcd = d & 7;
    const int l = d >> 3;
    const int rowBlk = xcd * 16 + (l >> 2);
    const int colBlk = l & 3;
    const long blockM = (long)rowBlk * 128;
    const long blockN = (long)colBlk * 128;

    floatx4 acc[4][4];
#pragma unroll
    for (int i = 0; i < 4; ++i)
#pragma unroll
        for (int j = 0; j < 4; ++j) acc[i][j] = (floatx4){0.f, 0.f, 0.f, 0.f};

    const int srow = tid >> 2;
    const int skoff = (tid & 3) * 8;
    const int ldsoff = srow * BK + skoff;
    const int fr = lane & 15;
    const int fq = (lane >> 4) * 8;

    for (int k0 = 0; k0 < KD; k0 += BK) {
        __syncthreads();
#pragma unroll
        for (int p = 0; p < 2; ++p) {
            const int row = srow + p * 64;
            const size_t aoff = (size_t)(blockM + row) * KD + k0 + skoff;
            const size_t boff = (size_t)(blockN + row) * KD + k0 + skoff;
            const int loff = ldsoff + p * 2048;
            __builtin_amdgcn_global_load_lds(
                (const __attribute__((address_space(1))) void*)(Ah + aoff),
                (__attribute__((address_space(3))) void*)(sAh + loff), 16, 0, 0);
            __builtin_amdgcn_global_load_lds(
                (const __attribute__((address_space(1))) void*)(BTh + boff),
                (__attribute__((address_space(3))) void*)(sBh + loff), 16, 0, 0);
            __builtin_amdgcn_global_load_lds(
                (const __attribute__((address_space(1))) void*)(BTl + boff),
                (__attribute__((address_space(3))) void*)(sBl + loff), 16, 0, 0);
        }
        __syncthreads();

        half8v fbh[4], fbl[4];
#pragma unroll
        for (int t = 0; t < 4; ++t) {
            fbh[t] = *(const half8v*)(sBh + (wn + t * 16 + fr) * BK + fq);
            fbl[t] = *(const half8v*)(sBl + (wn + t * 16 + fr) * BK + fq);
        }
#pragma unroll
        for (int i = 0; i < 4; ++i) {
            const half8v fah = *(const half8v*)(sAh + (wm + i * 16 + fr) * BK + fq);
#pragma unroll
            for (int j = 0; j < 4; ++j) {
                acc[i][j] = __builtin_amdgcn_mfma_f32_16x16x32_f16(fah, fbh[j], acc[i][j], 0, 0, 0);
                acc[i][j] = __builtin_amdgcn_mfma_f32_16x16x32_f16(fah, fbl[j], acc[i][j], 0, 0, 0);
            }
        }
    }

    const int ocol = lane & 15;
    float p[E_];
#pragma unroll
    for (int e = 0; e < E_; ++e) p[e] = 0.0f;
#pragma unroll
    for (int j = 0; j < 4; ++j) {
        const int gn = (int)blockN + wn + j * 16 + ocol;
        const float bj = bias[gn];
        const float4 w3a = *(const float4*)(w3 + (size_t)gn * E_);
        const float4 w3b = *(const float4*)(w3 + (size_t)gn * E_ + 4);
        float colsum = 0.0f;
#pragma unroll
        for (int i = 0; i < 4; ++i)
#pragma unroll
            for (int r = 0; r < 4; ++r)
                colsum += fmaxf(acc[i][j][r] * OSCALE + bj, 0.0f);
        p[0] += colsum * w3a.x; p[1] += colsum * w3a.y;
        p[2] += colsum * w3a.z; p[3] += colsum * w3a.w;
        p[4] += colsum * w3b.x; p[5] += colsum * w3b.y;
        p[6] += colsum * w3b.z; p[7] += colsum * w3b.w;
    }
#pragma unroll
    for (int e = 0; e < E_; ++e)
#pragma unroll
        for (int off = 32; off > 0; off >>= 1)
            p[e] += __shfl_xor(p[e], off);
#pragma unroll
    for (int e = 0; e < E_; ++e)
        if (lane == e) atomicAdd(&cl_acc[rowBlk * E_ + e], p[e]);
}

// ---------------------------------------------------------------------------
// Final+route (one launch, 64 blocks): every block redundantly computes the
// chunk logits, argmax, and hysteresis scan, then writes its routing-weight
// slice. Block 0 additionally writes EI/CL/stats.
// prev_expert_indices is dead in the reference (scan init zeros + is_first).
// ---------------------------------------------------------------------------
__global__ __launch_bounds__(256)
void final_route_kernel(const float* __restrict__ cl_acc, const float* __restrict__ b3,
                        float* __restrict__ out)
{
    __shared__ float cl[B_ * C_][E_];
    __shared__ int tops[B_ * C_];
    __shared__ int finals[B_ * C_];
    __shared__ int flips[B_];
    __shared__ float ent[B_ * C_];

    const int tid = threadIdx.x;

    if (tid < B_ * C_) {
        int best = 0;
        float bvv = -1e30f;
#pragma unroll
        for (int e = 0; e < E_; ++e) {
            const float v = cl_acc[tid * E_ + e] * (1.0f / CHUNK_) + b3[e];
            cl[tid][e] = v;
            if (v > bvv) { bvv = v; best = e; }   // first-max tiebreak == np.argmax
        }
        tops[tid] = best;
    }
    __syncthreads();

    if (tid < B_) {
        const int b = tid;
        int prev = 0, fl = 0;
        for (int c = 0; c < C_; ++c) {
            const int t = tops[b * C_ + c];
            int fin;
            if (c == 0) {
                fin = t;
            } else {
                const float cur = cl[b * C_ + c][t];
                const float pv = cl[b * C_ + c][prev];
                const bool sw = (cur - pv) > TAU_;
                if (sw) fl++;
                fin = sw ? t : prev;
            }
            finals[b * C_ + c] = fin;
            prev = fin;
        }
        flips[b] = fl;
    }
    __syncthreads();

    {
        const int tok = blockIdx.x * 256 + tid;
        const int b = tok >> 12;
        const int c = (tok & (S_ - 1)) >> 7;
        const int e = finals[b * C_ + c];
        float4 v0 = make_float4(e == 0 ? 1.f : 0.f, e == 1 ? 1.f : 0.f,
                                e == 2 ? 1.f : 0.f, e == 3 ? 1.f : 0.f);
        float4 v1 = make_float4(e == 4 ? 1.f : 0.f, e == 5 ? 1.f : 0.f,
                                e == 6 ? 1.f : 0.f, e == 7 ? 1.f : 0.f);
        float4* dst = (float4*)(out + OUT_RW + (size_t)tok * E_);
        dst[0] = v0;
        dst[1] = v1;
    }

    if (blockIdx.x == 0) {
        if (tid < B_ * C_) {
            out[OUT_EI + tid] = (float)finals[tid];
#pragma unroll
            for (int e = 0; e < E_; ++e) out[OUT_CL + tid * E_ + e] = cl[tid][e];
            float m = cl[tid][0];
            for (int e = 1; e < E_; ++e) m = fmaxf(m, cl[tid][e]);
            float pr[E_], s = 0.0f;
            for (int e = 0; e < E_; ++e) { pr[e] = expf(cl[tid][e] - m); s += pr[e]; }
            const float inv = 1.0f / s;
            float h = 0.0f;
            for (int e = 0; e < E_; ++e) { const float pe = pr[e] * inv; h -= pe * logf(pe + 1e-8f); }
            ent[tid] = h;
        }
        __syncthreads();
        if (tid == 0) {
            float esum = 0.0f;
            for (int i = 0; i < B_ * C_; ++i) esum += ent[i];
            out[OUT_GE] = esum / (float)(B_ * C_);

            int cnt[E_];
            for (int e = 0; e < E_; ++e) cnt[e] = 0;
            for (int i = 0; i < B_ * C_; ++i) cnt[finals[i]]++;
            float n2 = 0.0f;
            for (int e = 0; e < E_; ++e) {
                const float u = (float)cnt[e] / (float)(B_ * C_);
                out[OUT_UT + e] = u;
                n2 += u * u;
            }
            const int totfl = flips[0] + flips[1] + flips[2] + flips[3];
            out[OUT_FR] = (float)totfl / (float)(B_ * (C_ - 1));
            out[OUT_RC] = sqrtf(n2);
        }
    }
}

// ---------------------------------------------------------------------------
extern "C" void kernel_launch(void* const* d_in, const int* in_sizes, int n_in,
                              void* d_out, int out_size, void* d_ws, size_t ws_size,
                              hipStream_t stream)
{
    const float* x  = (const float*)d_in[0];
    const float* w1 = (const float*)d_in[2];
    const float* b1 = (const float*)d_in[3];
    const float* w2 = (const float*)d_in[4];
    const float* b2 = (const float*)d_in[5];
    const float* w3 = (const float*)d_in[6];
    const float* b3 = (const float*)d_in[7];
    float* out = (float*)d_out;

    half_t* xh   = (half_t*)d_ws;                    // 64 MB
    half_t* w1t  = xh + (size_t)M_ * D_;             // 4 MB
    half_t* h1h  = w1t + (size_t)H_ * D_;            // 32 MB
    half_t* w2th = h1h + (size_t)M_ * H_;            // 1 MB
    half_t* w2tl = w2th + (size_t)H2_ * H_;          // 1 MB
    float*  cl_acc = (float*)(w2tl + (size_t)H2_ * H_);  // 4 KB

    // 1) prep: x->f16 convert + transposes + cl_acc zero (one launch)
    prep_kernel<<<dim3(10753), dim3(256), 0, stream>>>(x, w1, w2, xh, w1t, w2th, w2tl, cl_acc);
    // 2) GEMM1: 256x256 8-phase counted-vmcnt schedule, 256 blocks (1/CU)
    gemm1_kernel<<<dim3(256), dim3(512), 0, stream>>>(xh, w1t, b1, h1h);
    // 3) GEMM2 fused through layer-3 + chunk-sum
    gemm2_fused_kernel<<<dim3(H2_ / 128, M_ / 128), dim3(256), 0, stream>>>(
        h1h, w2th, w2tl, b2, w3, cl_acc);
    // 4) finalize + routing weights (one launch)
    final_route_kernel<<<dim3(M_ / 256), dim3(256), 0, stream>>>(cl_acc, b3, out);
}

// Round 4
// 346.981 us; speedup vs baseline: 1.0675x; 1.0675x over previous
//
#include <hip/hip_runtime.h>
#include <math.h>

typedef _Float16 half_t;
typedef __attribute__((ext_vector_type(4))) _Float16 half4v;
typedef __attribute__((ext_vector_type(8))) _Float16 half8v;
typedef __attribute__((ext_vector_type(4))) float floatx4;

constexpr int B_ = 4, S_ = 4096, D_ = 2048, H_ = 1024, H2_ = 512, E_ = 8;
constexpr int CHUNK_ = 128;
constexpr int C_ = S_ / CHUNK_;          // 32
constexpr int M_ = B_ * S_;              // 16384
constexpr float TAU_ = 0.7f;
// Precision ledger (measured): full split absmax=0 (R2); x/W1 pure-f16 +
// W2 split kept -> absmax = 2^-9 (R4-R6), 60x under threshold. W2 residual
// kept: h1>=0 (positive mean) makes W2-rounding coherent through the chunk
// mean; x/W1 rounding is token-incoherent -> averages out ~sqrt(128).
constexpr float WSCALE = 64.0f, OSCALE = 1.0f / 64.0f;

constexpr int OUT_RW = 0;
constexpr int OUT_EI = OUT_RW + B_ * S_ * E_;
constexpr int OUT_CL = OUT_EI + B_ * C_;
constexpr int OUT_GE = OUT_CL + B_ * C_ * E_;
constexpr int OUT_UT = OUT_GE + 1;
constexpr int OUT_FR = OUT_UT + E_;
constexpr int OUT_RC = OUT_FR + 1;

// ---------------------------------------------------------------------------
// Prep (one launch):
//   blocks [0,8192):       x fp32 -> f16 (1024 float4 per block)
//   blocks [8192,10240):   w1 [D,H] -> w1t [H,D] f16
//   blocks [10240,10752):  w2 [H,H2] -> w2t hi/lo [H2,H], pre-scaled x64
//   block  10752:          zero cl_acc
// ---------------------------------------------------------------------------
__global__ __launch_bounds__(256)
void prep_kernel(const float* __restrict__ x, const float* __restrict__ w1,
                 const float* __restrict__ w2,
                 half_t* __restrict__ xh, half_t* __restrict__ w1t,
                 half_t* __restrict__ w2th, half_t* __restrict__ w2tl,
                 float* __restrict__ cl_acc)
{
    __shared__ float tile[32][33];
    const int tx = threadIdx.x & 31;
    const int ty = threadIdx.x >> 5;
    const int bid = blockIdx.x;

    if (bid < 8192) {                     // convert x: 1024 float4 per block
        const int base = bid * 1024 + threadIdx.x;
#pragma unroll
        for (int p = 0; p < 4; ++p) {
            const int i = base + p * 256;
            const float4 v = ((const float4*)x)[i];
            half4v h;
            h.x = (half_t)v.x; h.y = (half_t)v.y; h.z = (half_t)v.z; h.w = (half_t)v.w;
            ((half4v*)xh)[i] = h;
        }
    } else if (bid < 10240) {             // w1 transpose -> f16
        const int b2 = bid - 8192;
        const int n0 = (b2 & 31) * 32;    // H_/32 = 32
        const int k0 = (b2 >> 5) * 32;    // D_/32 = 64
#pragma unroll
        for (int r = 0; r < 4; ++r)
            tile[ty + r * 8][tx] = w1[(size_t)(k0 + ty + r * 8) * H_ + n0 + tx];
        __syncthreads();
#pragma unroll
        for (int r = 0; r < 4; ++r)
            w1t[(size_t)(n0 + ty + r * 8) * D_ + k0 + tx] = (half_t)tile[tx][ty + r * 8];
    } else if (bid < 10752) {             // w2 transpose + split
        const int b2 = bid - 10240;
        const int n0 = (b2 & 15) * 32;    // H2_/32 = 16
        const int k0 = (b2 >> 4) * 32;    // H_/32 = 32
#pragma unroll
        for (int r = 0; r < 4; ++r)
            tile[ty + r * 8][tx] = w2[(size_t)(k0 + ty + r * 8) * H2_ + n0 + tx];
        __syncthreads();
#pragma unroll
        for (int r = 0; r < 4; ++r) {
            const float v = tile[tx][ty + r * 8] * WSCALE;
            const half_t h = (half_t)v;
            const size_t off = (size_t)(n0 + ty + r * 8) * H_ + k0 + tx;
            w2th[off] = h;
            w2tl[off] = (half_t)(v - (float)h);
        }
    } else {                              // zero chunk-logit accumulator
        for (int i = threadIdx.x; i < B_ * C_ * E_; i += 256) cl_acc[i] = 0.0f;
    }
}

// ---------------------------------------------------------------------------
// GEMM1: h1 = relu(xh @ w1 + b1) -> f16.
// R7: 256x256x(BK=64) 8-phase counted-vmcnt schedule (learn_hip m201 port).
// R8: paired-row LDS layout -> bank conflicts = 0 (verified by PMC).
// R9 (REVERTED): cross-phase register dbuf regressed 83->112 us; extra live
//   sets + counted lgkm fought the compiler's own waits.
// R10: pin ds_read issue BEFORE the head barrier with sched_barrier(0).
//   Theory: R2's 1556 cyc/phase == fully-serial reads(576)+MFMA(621)+ovh.
//   The intended overlap (LDS FIFO drains reads during barrier wait;
//   early-cleared waves MFMA while later waves' reads process) requires the
//   ds_reads to ISSUE pre-barrier; nothing pinned them there, and LLVM
//   sinks loads toward first use (after barrier+lgkm), which serializes.
//   Two sched_barrier(0) pins (after read group, before s_barrier) enforce
//   the issue order at zero runtime cost. K-order unchanged (absmax canary).
//   - half-slot lifecycle / counted vmcnt(6) unchanged from R7 (verified):
//     h0 read phases 1-2, h1 phases 3-4; restage >=1 barrier after last
//     read; ONE vmcnt(6) per K-tile, never 0 in the main loop.
// ---------------------------------------------------------------------------
__device__ __forceinline__ int lds_off_g(int row, int q)
{
    // half-index into a k-half tile for (row, k-quarter q)
    const int line = row >> 1;
    const int sl = (((row & 1) << 2) | q) ^ (line & 7);
    return line * 64 + sl * 8;
}

__device__ __forceinline__ void stage_half_g1(const half_t* __restrict__ g,
                                              half_t* l, int tid)
{
    // LDS[line][s] <- global(row = 2*line + p, k = q*8) with p*4+q = s^(line&7)
    const int s = tid & 7;
#pragma unroll
    for (int r = 0; r < 2; ++r) {
        const int line = r * 64 + (tid >> 3);
        const int u = s ^ (line & 7);
        const int row = line * 2 + (u >> 2);
        const int kq = (u & 3) * 8;
        __builtin_amdgcn_global_load_lds(
            (const __attribute__((address_space(1))) void*)(g + (size_t)row * D_ + kq),
            (__attribute__((address_space(3))) void*)(l + (r * 512 + tid) * 8),
            16, 0, 0);
    }
}

__global__ __launch_bounds__(512, 2)
void gemm1_kernel(const half_t* __restrict__ Ah,
                  const half_t* __restrict__ BTh,
                  const float* __restrict__ bias, half_t* __restrict__ outh)
{
    constexpr int KD = D_;        // 2048
    constexpr int ND = H_;        // 1024
    constexpr int NT = KD / 64;   // 32 K-tiles

    __shared__ __align__(16) half_t sA[2][2][256 * 32];   // [dbuf][khalf]
    __shared__ __align__(16) half_t sB[2][2][256 * 32];

    const int tid = threadIdx.x;
    const int lane = tid & 63;
    const int wave = tid >> 6;
    const int wRow = (wave >> 2) * 128;     // 2 M-wave-groups
    const int wCol = (wave & 3) * 64;       // 4 N-wave-groups
    const int fr = lane & 15;
    const int q = lane >> 4;                // k-quarter

    // XCD-bijective swizzle: bid%8 = XCD; each XCD owns a contiguous
    // 8-M-block stripe x all 4 N-blocks (B panels + A rows L2-local).
    const int bid = blockIdx.x;
    const long blockM = (long)((bid & 7) * 8 + (bid >> 5)) * 256;
    const long blockN = (long)((bid >> 3) & 3) * 256;

    const half_t* gA = Ah + (size_t)blockM * KD;
    const half_t* gB = BTh + (size_t)blockN * KD;

    floatx4 acc[8][4];
#pragma unroll
    for (int i = 0; i < 8; ++i)
#pragma unroll
        for (int j = 0; j < 4; ++j) acc[i][j] = (floatx4){0.f, 0.f, 0.f, 0.f};

    // Prologue: tile0 complete + steady-state 3 halves of tile1 in flight.
    stage_half_g1(gA,      sA[0][0], tid);   // A0.h0
    stage_half_g1(gB,      sB[0][0], tid);   // B0.h0
    stage_half_g1(gA + 32, sA[0][1], tid);   // A0.h1
    stage_half_g1(gB + 32, sB[0][1], tid);   // B0.h1
    stage_half_g1(gB + 64, sB[1][0], tid);   // B1.h0   (as-if (t-1,P2))
    stage_half_g1(gA + 64, sA[1][0], tid);   // A1.h0   (as-if (t-1,P3))
    stage_half_g1(gB + 96, sB[1][1], tid);   // B1.h1   (as-if (t-1,P4))
    asm volatile("s_waitcnt vmcnt(6)" ::: "memory");   // tile0 landed
    __builtin_amdgcn_s_barrier();
    __builtin_amdgcn_sched_barrier(0);

    half8v bfr[4];

#define G1_PHASE(BUF, H, MB, STAGE_STMT, TAIL_STMT)                            \
    {                                                                          \
        half8v afr[4];                                                         \
        if ((MB) == 0) {                                                       \
            _Pragma("unroll")                                                  \
            for (int n = 0; n < 4; ++n)                                        \
                bfr[n] = *(const half8v*)(sB[BUF][H] +                         \
                          lds_off_g(wCol + n * 16 + fr, q));                   \
        }                                                                      \
        _Pragma("unroll")                                                      \
        for (int m = 0; m < 4; ++m)                                            \
            afr[m] = *(const half8v*)(sA[BUF][H] +                             \
                      lds_off_g(wRow + (MB) + m * 16 + fr, q));                \
        __builtin_amdgcn_sched_barrier(0);  /* pin ds_read issue pre-barrier */\
        STAGE_STMT;                                                            \
        __builtin_amdgcn_sched_barrier(0);  /* pin stage issue pre-barrier */  \
        __builtin_amdgcn_s_barrier();                                          \
        asm volatile("s_waitcnt lgkmcnt(0)" ::: "memory");                     \
        __builtin_amdgcn_sched_barrier(0);                                     \
        __builtin_amdgcn_s_setprio(1);                                         \
        _Pragma("unroll")                                                      \
        for (int m = 0; m < 4; ++m)                                            \
            _Pragma("unroll")                                                  \
            for (int n = 0; n < 4; ++n)                                        \
                acc[(MB) / 16 + m][n] = __builtin_amdgcn_mfma_f32_16x16x32_f16(\
                    afr[m], bfr[n], acc[(MB) / 16 + m][n], 0, 0, 0);           \
        __builtin_amdgcn_s_setprio(0);                                         \
        TAIL_STMT;                                                             \
        __builtin_amdgcn_s_barrier();                                          \
        __builtin_amdgcn_sched_barrier(0);                                     \
    }

#define G1_TILE(BUF, T)                                                        \
    {                                                                          \
        G1_PHASE(BUF, 0, 0,                                                    \
            if ((T) + 1 < NT)                                                  \
                stage_half_g1(gA + ((T) + 1) * 64 + 32, sA[(BUF) ^ 1][1], tid),\
            );                                                                 \
        G1_PHASE(BUF, 0, 64,                                                   \
            if ((T) + 2 < NT)                                                  \
                stage_half_g1(gB + ((T) + 2) * 64, sB[BUF][0], tid),           \
            );                                                                 \
        G1_PHASE(BUF, 1, 0,                                                    \
            if ((T) + 2 < NT)                                                  \
                stage_half_g1(gA + ((T) + 2) * 64, sA[BUF][0], tid),           \
            );                                                                 \
        G1_PHASE(BUF, 1, 64,                                                   \
            if ((T) + 2 < NT)                                                  \
                stage_half_g1(gB + ((T) + 2) * 64 + 32, sB[BUF][1], tid),      \
            if ((T) < NT - 2) {                                                \
                asm volatile("s_waitcnt vmcnt(6)" ::: "memory");               \
            } else if ((T) == NT - 2) {                                        \
                asm volatile("s_waitcnt vmcnt(0)" ::: "memory");               \
            });                                                                \
    }

    for (int t = 0; t < NT; t += 2) {
        G1_TILE(0, t);
        G1_TILE(1, t + 1);
    }
#undef G1_TILE
#undef G1_PHASE

    // Epilogue: relu(acc + bias) -> f16 store (same C/D mapping as before)
    const int orow = (lane >> 4) * 4;
    const int ocol = lane & 15;
#pragma unroll
    for (int n = 0; n < 4; ++n) {
        const long gn = blockN + wCol + n * 16 + ocol;
        const float bj = bias[gn];
#pragma unroll
        for (int m = 0; m < 8; ++m) {
#pragma unroll
            for (int r = 0; r < 4; ++r) {
                const float v = fmaxf(acc[m][n][r] + bj, 0.0f);
                outh[(size_t)(blockM + wRow + m * 16 + orow + r) * ND + gn] = (half_t)v;
            }
        }
    }
}

// ---------------------------------------------------------------------------
// GEMM2 fused: relu(h1 @ w2 + b2) @ w3, chunk-summed into cl_acc via
// device-scope atomics. h2 never materialized. f16x2 (W2 split kept).
// ---------------------------------------------------------------------------
__global__ __launch_bounds__(256, 3)
void gemm2_fused_kernel(const half_t* __restrict__ Ah,
                        const half_t* __restrict__ BTh, const half_t* __restrict__ BTl,
                        const float* __restrict__ bias, const float* __restrict__ w3,
                        float* __restrict__ cl_acc)
{
    constexpr int KD = H_, BK = 32;
    __shared__ __align__(16) half_t sAh[128 * BK];
    __shared__ __align__(16) half_t sBh[128 * BK];
    __shared__ __align__(16) half_t sBl[128 * BK];

    const int tid = threadIdx.x;
    const int lane = tid & 63;
    const int wave = tid >> 6;
    const int wm = (wave & 1) * 64;
    const int wn = (wave >> 1) * 64;
    const int d = blockIdx.y * 4 + blockIdx.x;
    const int xcd = d & 7;
    const int l = d >> 3;
    const int rowBlk = xcd * 16 + (l >> 2);
    const int colBlk = l & 3;
    const long blockM = (long)rowBlk * 128;
    const long blockN = (long)colBlk * 128;

    floatx4 acc[4][4];
#pragma unroll
    for (int i = 0; i < 4; ++i)
#pragma unroll
        for (int j = 0; j < 4; ++j) acc[i][j] = (floatx4){0.f, 0.f, 0.f, 0.f};

    const int srow = tid >> 2;
    const int skoff = (tid & 3) * 8;
    const int ldsoff = srow * BK + skoff;
    const int fr = lane & 15;
    const int fq = (lane >> 4) * 8;

    for (int k0 = 0; k0 < KD; k0 += BK) {
        __syncthreads();
#pragma unroll
        for (int p = 0; p < 2; ++p) {
            const int row = srow + p * 64;
            const size_t aoff = (size_t)(blockM + row) * KD + k0 + skoff;
            const size_t boff = (size_t)(blockN + row) * KD + k0 + skoff;
            const int loff = ldsoff + p * 2048;
            __builtin_amdgcn_global_load_lds(
                (const __attribute__((address_space(1))) void*)(Ah + aoff),
                (__attribute__((address_space(3))) void*)(sAh + loff), 16, 0, 0);
            __builtin_amdgcn_global_load_lds(
                (const __attribute__((address_space(1))) void*)(BTh + boff),
                (__attribute__((address_space(3))) void*)(sBh + loff), 16, 0, 0);
            __builtin_amdgcn_global_load_lds(
                (const __attribute__((address_space(1))) void*)(BTl + boff),
                (__attribute__((address_space(3))) void*)(sBl + loff), 16, 0, 0);
        }
        __syncthreads();

        half8v fbh[4], fbl[4];
#pragma unroll
        for (int t = 0; t < 4; ++t) {
            fbh[t] = *(const half8v*)(sBh + (wn + t * 16 + fr) * BK + fq);
            fbl[t] = *(const half8v*)(sBl + (wn + t * 16 + fr) * BK + fq);
        }
#pragma unroll
        for (int i = 0; i < 4; ++i) {
            const half8v fah = *(const half8v*)(sAh + (wm + i * 16 + fr) * BK + fq);
#pragma unroll
            for (int j = 0; j < 4; ++j) {
                acc[i][j] = __builtin_amdgcn_mfma_f32_16x16x32_f16(fah, fbh[j], acc[i][j], 0, 0, 0);
                acc[i][j] = __builtin_amdgcn_mfma_f32_16x16x32_f16(fah, fbl[j], acc[i][j], 0, 0, 0);
            }
        }
    }

    const int ocol = lane & 15;
    float p[E_];
#pragma unroll
    for (int e = 0; e < E_; ++e) p[e] = 0.0f;
#pragma unroll
    for (int j = 0; j < 4; ++j) {
        const int gn = (int)blockN + wn + j * 16 + ocol;
        const float bj = bias[gn];
        const float4 w3a = *(const float4*)(w3 + (size_t)gn * E_);
        const float4 w3b = *(const float4*)(w3 + (size_t)gn * E_ + 4);
        float colsum = 0.0f;
#pragma unroll
        for (int i = 0; i < 4; ++i)
#pragma unroll
            for (int r = 0; r < 4; ++r)
                colsum += fmaxf(acc[i][j][r] * OSCALE + bj, 0.0f);
        p[0] += colsum * w3a.x; p[1] += colsum * w3a.y;
        p[2] += colsum * w3a.z; p[3] += colsum * w3a.w;
        p[4] += colsum * w3b.x; p[5] += colsum * w3b.y;
        p[6] += colsum * w3b.z; p[7] += colsum * w3b.w;
    }
#pragma unroll
    for (int e = 0; e < E_; ++e)
#pragma unroll
        for (int off = 32; off > 0; off >>= 1)
            p[e] += __shfl_xor(p[e], off);
#pragma unroll
    for (int e = 0; e < E_; ++e)
        if (lane == e) atomicAdd(&cl_acc[rowBlk * E_ + e], p[e]);
}

// ---------------------------------------------------------------------------
// Final+route (one launch, 64 blocks): every block redundantly computes the
// chunk logits, argmax, and hysteresis scan, then writes its routing-weight
// slice. Block 0 additionally writes EI/CL/stats.
// prev_expert_indices is dead in the reference (scan init zeros + is_first).
// ---------------------------------------------------------------------------
__global__ __launch_bounds__(256)
void final_route_kernel(const float* __restrict__ cl_acc, const float* __restrict__ b3,
                        float* __restrict__ out)
{
    __shared__ float cl[B_ * C_][E_];
    __shared__ int tops[B_ * C_];
    __shared__ int finals[B_ * C_];
    __shared__ int flips[B_];
    __shared__ float ent[B_ * C_];

    const int tid = threadIdx.x;

    if (tid < B_ * C_) {
        int best = 0;
        float bvv = -1e30f;
#pragma unroll
        for (int e = 0; e < E_; ++e) {
            const float v = cl_acc[tid * E_ + e] * (1.0f / CHUNK_) + b3[e];
            cl[tid][e] = v;
            if (v > bvv) { bvv = v; best = e; }   // first-max tiebreak == np.argmax
        }
        tops[tid] = best;
    }
    __syncthreads();

    if (tid < B_) {
        const int b = tid;
        int prev = 0, fl = 0;
        for (int c = 0; c < C_; ++c) {
            const int t = tops[b * C_ + c];
            int fin;
            if (c == 0) {
                fin = t;
            } else {
                const float cur = cl[b * C_ + c][t];
                const float pv = cl[b * C_ + c][prev];
                const bool sw = (cur - pv) > TAU_;
                if (sw) fl++;
                fin = sw ? t : prev;
            }
            finals[b * C_ + c] = fin;
            prev = fin;
        }
        flips[b] = fl;
    }
    __syncthreads();

    {
        const int tok = blockIdx.x * 256 + tid;
        const int b = tok >> 12;
        const int c = (tok & (S_ - 1)) >> 7;
        const int e = finals[b * C_ + c];
        float4 v0 = make_float4(e == 0 ? 1.f : 0.f, e == 1 ? 1.f : 0.f,
                                e == 2 ? 1.f : 0.f, e == 3 ? 1.f : 0.f);
        float4 v1 = make_float4(e == 4 ? 1.f : 0.f, e == 5 ? 1.f : 0.f,
                                e == 6 ? 1.f : 0.f, e == 7 ? 1.f : 0.f);
        float4* dst = (float4*)(out + OUT_RW + (size_t)tok * E_);
        dst[0] = v0;
        dst[1] = v1;
    }

    if (blockIdx.x == 0) {
        if (tid < B_ * C_) {
            out[OUT_EI + tid] = (float)finals[tid];
#pragma unroll
            for (int e = 0; e < E_; ++e) out[OUT_CL + tid * E_ + e] = cl[tid][e];
            float m = cl[tid][0];
            for (int e = 1; e < E_; ++e) m = fmaxf(m, cl[tid][e]);
            float pr[E_], s = 0.0f;
            for (int e = 0; e < E_; ++e) { pr[e] = expf(cl[tid][e] - m); s += pr[e]; }
            const float inv = 1.0f / s;
            float h = 0.0f;
            for (int e = 0; e < E_; ++e) { const float pe = pr[e] * inv; h -= pe * logf(pe + 1e-8f); }
            ent[tid] = h;
        }
        __syncthreads();
        if (tid == 0) {
            float esum = 0.0f;
            for (int i = 0; i < B_ * C_; ++i) esum += ent[i];
            out[OUT_GE] = esum / (float)(B_ * C_);

            int cnt[E_];
            for (int e = 0; e < E_; ++e) cnt[e] = 0;
            for (int i = 0; i < B_ * C_; ++i) cnt[finals[i]]++;
            float n2 = 0.0f;
            for (int e = 0; e < E_; ++e) {
                const float u = (float)cnt[e] / (float)(B_ * C_);
                out[OUT_UT + e] = u;
                n2 += u * u;
            }
            const int totfl = flips[0] + flips[1] + flips[2] + flips[3];
            out[OUT_FR] = (float)totfl / (float)(B_ * (C_ - 1));
            out[OUT_RC] = sqrtf(n2);
        }
    }
}

// ---------------------------------------------------------------------------
extern "C" void kernel_launch(void* const* d_in, const int* in_sizes, int n_in,
                              void* d_out, int out_size, void* d_ws, size_t ws_size,
                              hipStream_t stream)
{
    const float* x  = (const float*)d_in[0];
    const float* w1 = (const float*)d_in[2];
    const float* b1 = (const float*)d_in[3];
    const float* w2 = (const float*)d_in[4];
    const float* b2 = (const float*)d_in[5];
    const float* w3 = (const float*)d_in[6];
    const float* b3 = (const float*)d_in[7];
    float* out = (float*)d_out;

    half_t* xh   = (half_t*)d_ws;                    // 64 MB
    half_t* w1t  = xh + (size_t)M_ * D_;             // 4 MB
    half_t* h1h  = w1t + (size_t)H_ * D_;            // 32 MB
    half_t* w2th = h1h + (size_t)M_ * H_;            // 1 MB
    half_t* w2tl = w2th + (size_t)H2_ * H_;          // 1 MB
    float*  cl_acc = (float*)(w2tl + (size_t)H2_ * H_);  // 4 KB

    // 1) prep: x->f16 convert + transposes + cl_acc zero (one launch)
    prep_kernel<<<dim3(10753), dim3(256), 0, stream>>>(x, w1, w2, xh, w1t, w2th, w2tl, cl_acc);
    // 2) GEMM1: 256x256 8-phase counted-vmcnt schedule, 256 blocks (1/CU)
    gemm1_kernel<<<dim3(256), dim3(512), 0, stream>>>(xh, w1t, b1, h1h);
    // 3) GEMM2 fused through layer-3 + chunk-sum
    gemm2_fused_kernel<<<dim3(H2_ / 128, M_ / 128), dim3(256), 0, stream>>>(
        h1h, w2th, w2tl, b2, w3, cl_acc);
    // 4) finalize + routing weights (one launch)
    final_route_kernel<<<dim3(M_ / 256), dim3(256), 0, stream>>>(cl_acc, b3, out);
}

// Round 5
// 342.467 us; speedup vs baseline: 1.0816x; 1.0132x over previous
//
#include <hip/hip_runtime.h>
#include <math.h>

typedef _Float16 half_t;
typedef __attribute__((ext_vector_type(4))) _Float16 half4v;
typedef __attribute__((ext_vector_type(8))) _Float16 half8v;
typedef __attribute__((ext_vector_type(4))) float floatx4;

constexpr int B_ = 4, S_ = 4096, D_ = 2048, H_ = 1024, H2_ = 512, E_ = 8;
constexpr int CHUNK_ = 128;
constexpr int C_ = S_ / CHUNK_;          // 32
constexpr int M_ = B_ * S_;              // 16384
constexpr float TAU_ = 0.7f;
// Precision ledger (measured): full split absmax=0 (R2); x/W1 pure-f16 +
// W2 split kept -> absmax = 2^-9 (R4-R6), 60x under threshold. W2 residual
// kept: h1>=0 (positive mean) makes W2-rounding coherent through the chunk
// mean; x/W1 rounding is token-incoherent -> averages out ~sqrt(128).
constexpr float WSCALE = 64.0f, OSCALE = 1.0f / 64.0f;

constexpr int OUT_RW = 0;
constexpr int OUT_EI = OUT_RW + B_ * S_ * E_;
constexpr int OUT_CL = OUT_EI + B_ * C_;
constexpr int OUT_GE = OUT_CL + B_ * C_ * E_;
constexpr int OUT_UT = OUT_GE + 1;
constexpr int OUT_FR = OUT_UT + E_;
constexpr int OUT_RC = OUT_FR + 1;

// ---------------------------------------------------------------------------
// Prep (one launch):
//   blocks [0,8192):       x fp32 -> f16 (512 half8 per block, 16B stores)
//   blocks [8192,10240):   w1 [D,H] -> w1t [H,D] f16
//   blocks [10240,10752):  w2 [H,H2] -> w2t hi/lo [H2,H], pre-scaled x64
//   block  10752:          zero cl_acc
// ---------------------------------------------------------------------------
__global__ __launch_bounds__(256)
void prep_kernel(const float* __restrict__ x, const float* __restrict__ w1,
                 const float* __restrict__ w2,
                 half_t* __restrict__ xh, half_t* __restrict__ w1t,
                 half_t* __restrict__ w2th, half_t* __restrict__ w2tl,
                 float* __restrict__ cl_acc)
{
    __shared__ float tile[32][33];
    const int tx = threadIdx.x & 31;
    const int ty = threadIdx.x >> 5;
    const int bid = blockIdx.x;

    if (bid < 8192) {                     // convert x: 16B/lane stores
        const int base = bid * 512 + threadIdx.x;   // half8 index space
#pragma unroll
        for (int p = 0; p < 2; ++p) {
            const int j = base + p * 256;
            const float4 a = ((const float4*)x)[2 * j];
            const float4 b = ((const float4*)x)[2 * j + 1];
            half8v h;
            h[0] = (half_t)a.x; h[1] = (half_t)a.y;
            h[2] = (half_t)a.z; h[3] = (half_t)a.w;
            h[4] = (half_t)b.x; h[5] = (half_t)b.y;
            h[6] = (half_t)b.z; h[7] = (half_t)b.w;
            ((half8v*)xh)[j] = h;
        }
    } else if (bid < 10240) {             // w1 transpose -> f16
        const int b2 = bid - 8192;
        const int n0 = (b2 & 31) * 32;    // H_/32 = 32
        const int k0 = (b2 >> 5) * 32;    // D_/32 = 64
#pragma unroll
        for (int r = 0; r < 4; ++r)
            tile[ty + r * 8][tx] = w1[(size_t)(k0 + ty + r * 8) * H_ + n0 + tx];
        __syncthreads();
#pragma unroll
        for (int r = 0; r < 4; ++r)
            w1t[(size_t)(n0 + ty + r * 8) * D_ + k0 + tx] = (half_t)tile[tx][ty + r * 8];
    } else if (bid < 10752) {             // w2 transpose + split
        const int b2 = bid - 10240;
        const int n0 = (b2 & 15) * 32;    // H2_/32 = 16
        const int k0 = (b2 >> 4) * 32;    // H_/32 = 32
#pragma unroll
        for (int r = 0; r < 4; ++r)
            tile[ty + r * 8][tx] = w2[(size_t)(k0 + ty + r * 8) * H2_ + n0 + tx];
        __syncthreads();
#pragma unroll
        for (int r = 0; r < 4; ++r) {
            const float v = tile[tx][ty + r * 8] * WSCALE;
            const half_t h = (half_t)v;
            const size_t off = (size_t)(n0 + ty + r * 8) * H_ + k0 + tx;
            w2th[off] = h;
            w2tl[off] = (half_t)(v - (float)h);
        }
    } else {                              // zero chunk-logit accumulator
        for (int i = threadIdx.x; i < B_ * C_ * E_; i += 256) cl_acc[i] = 0.0f;
    }
}

// ---------------------------------------------------------------------------
// GEMM1: h1 = relu(xh @ w1 + b1) -> f16.
// R7: 256x256x(BK=64) 8-phase counted-vmcnt schedule (learn_hip m201 port).
// R8: paired-row LDS layout -> bank conflicts = 0 (verified by PMC).
// R9 (REVERTED): cross-phase register dbuf regressed 83->112 us.
// R10 (REVERTED): sched_barrier read pins were neutral (+2 us) -> reads
//   already issue pre-barrier; sunk-load theory dead.
// R11: #pragma unroll 1 on the K-loop. Audit: serial template should cost
//   ~850-950 cyc/phase (MFMA 621 + LDS 192 @256B/clk + issue/barriers) and
//   m201's verified 1563 TF = 824 cyc/phase with the SAME source template.
//   Measured 1556 -> ~650 cyc/phase residual no data-path model explains.
//   Suspect: unrolled 16-iter x ~700-inst body = 22-45 KB text > 32 KB
//   I-cache -> front-end streams the whole body from L2 every iteration.
//   unroll 1 keeps the body ~2.5 KB (I-cache resident). Zero numeric change.
// ---------------------------------------------------------------------------
__device__ __forceinline__ int lds_off_g(int row, int q)
{
    // half-index into a k-half tile for (row, k-quarter q)
    const int line = row >> 1;
    const int sl = (((row & 1) << 2) | q) ^ (line & 7);
    return line * 64 + sl * 8;
}

__device__ __forceinline__ void stage_half_g1(const half_t* __restrict__ g,
                                              half_t* l, int tid)
{
    // LDS[line][s] <- global(row = 2*line + p, k = q*8) with p*4+q = s^(line&7)
    const int s = tid & 7;
#pragma unroll
    for (int r = 0; r < 2; ++r) {
        const int line = r * 64 + (tid >> 3);
        const int u = s ^ (line & 7);
        const int row = line * 2 + (u >> 2);
        const int kq = (u & 3) * 8;
        __builtin_amdgcn_global_load_lds(
            (const __attribute__((address_space(1))) void*)(g + (size_t)row * D_ + kq),
            (__attribute__((address_space(3))) void*)(l + (r * 512 + tid) * 8),
            16, 0, 0);
    }
}

__global__ __launch_bounds__(512, 2)
void gemm1_kernel(const half_t* __restrict__ Ah,
                  const half_t* __restrict__ BTh,
                  const float* __restrict__ bias, half_t* __restrict__ outh)
{
    constexpr int KD = D_;        // 2048
    constexpr int ND = H_;        // 1024
    constexpr int NT = KD / 64;   // 32 K-tiles

    __shared__ __align__(16) half_t sA[2][2][256 * 32];   // [dbuf][khalf]
    __shared__ __align__(16) half_t sB[2][2][256 * 32];

    const int tid = threadIdx.x;
    const int lane = tid & 63;
    const int wave = tid >> 6;
    const int wRow = (wave >> 2) * 128;     // 2 M-wave-groups
    const int wCol = (wave & 3) * 64;       // 4 N-wave-groups
    const int fr = lane & 15;
    const int q = lane >> 4;                // k-quarter

    // XCD-bijective swizzle: bid%8 = XCD; each XCD owns a contiguous
    // 8-M-block stripe x all 4 N-blocks (B panels + A rows L2-local).
    const int bid = blockIdx.x;
    const long blockM = (long)((bid & 7) * 8 + (bid >> 5)) * 256;
    const long blockN = (long)((bid >> 3) & 3) * 256;

    const half_t* gA = Ah + (size_t)blockM * KD;
    const half_t* gB = BTh + (size_t)blockN * KD;

    floatx4 acc[8][4];
#pragma unroll
    for (int i = 0; i < 8; ++i)
#pragma unroll
        for (int j = 0; j < 4; ++j) acc[i][j] = (floatx4){0.f, 0.f, 0.f, 0.f};

    // Prologue: tile0 complete + steady-state 3 halves of tile1 in flight.
    stage_half_g1(gA,      sA[0][0], tid);   // A0.h0
    stage_half_g1(gB,      sB[0][0], tid);   // B0.h0
    stage_half_g1(gA + 32, sA[0][1], tid);   // A0.h1
    stage_half_g1(gB + 32, sB[0][1], tid);   // B0.h1
    stage_half_g1(gB + 64, sB[1][0], tid);   // B1.h0   (as-if (t-1,P2))
    stage_half_g1(gA + 64, sA[1][0], tid);   // A1.h0   (as-if (t-1,P3))
    stage_half_g1(gB + 96, sB[1][1], tid);   // B1.h1   (as-if (t-1,P4))
    asm volatile("s_waitcnt vmcnt(6)" ::: "memory");   // tile0 landed
    __builtin_amdgcn_s_barrier();
    __builtin_amdgcn_sched_barrier(0);

    half8v bfr[4];

#define G1_PHASE(BUF, H, MB, STAGE_STMT, TAIL_STMT)                            \
    {                                                                          \
        half8v afr[4];                                                         \
        if ((MB) == 0) {                                                       \
            _Pragma("unroll")                                                  \
            for (int n = 0; n < 4; ++n)                                        \
                bfr[n] = *(const half8v*)(sB[BUF][H] +                         \
                          lds_off_g(wCol + n * 16 + fr, q));                   \
        }                                                                      \
        _Pragma("unroll")                                                      \
        for (int m = 0; m < 4; ++m)                                            \
            afr[m] = *(const half8v*)(sA[BUF][H] +                             \
                      lds_off_g(wRow + (MB) + m * 16 + fr, q));                \
        STAGE_STMT;                                                            \
        __builtin_amdgcn_s_barrier();                                          \
        asm volatile("s_waitcnt lgkmcnt(0)" ::: "memory");                     \
        __builtin_amdgcn_sched_barrier(0);                                     \
        __builtin_amdgcn_s_setprio(1);                                         \
        _Pragma("unroll")                                                      \
        for (int m = 0; m < 4; ++m)                                            \
            _Pragma("unroll")                                                  \
            for (int n = 0; n < 4; ++n)                                        \
                acc[(MB) / 16 + m][n] = __builtin_amdgcn_mfma_f32_16x16x32_f16(\
                    afr[m], bfr[n], acc[(MB) / 16 + m][n], 0, 0, 0);           \
        __builtin_amdgcn_s_setprio(0);                                         \
        TAIL_STMT;                                                             \
        __builtin_amdgcn_s_barrier();                                          \
        __builtin_amdgcn_sched_barrier(0);                                     \
    }

#define G1_TILE(BUF, T)                                                        \
    {                                                                          \
        G1_PHASE(BUF, 0, 0,                                                    \
            if ((T) + 1 < NT)                                                  \
                stage_half_g1(gA + ((T) + 1) * 64 + 32, sA[(BUF) ^ 1][1], tid),\
            );                                                                 \
        G1_PHASE(BUF, 0, 64,                                                   \
            if ((T) + 2 < NT)                                                  \
                stage_half_g1(gB + ((T) + 2) * 64, sB[BUF][0], tid),           \
            );                                                                 \
        G1_PHASE(BUF, 1, 0,                                                    \
            if ((T) + 2 < NT)                                                  \
                stage_half_g1(gA + ((T) + 2) * 64, sA[BUF][0], tid),           \
            );                                                                 \
        G1_PHASE(BUF, 1, 64,                                                   \
            if ((T) + 2 < NT)                                                  \
                stage_half_g1(gB + ((T) + 2) * 64 + 32, sB[BUF][1], tid),      \
            if ((T) < NT - 2) {                                                \
                asm volatile("s_waitcnt vmcnt(6)" ::: "memory");               \
            } else if ((T) == NT - 2) {                                        \
                asm volatile("s_waitcnt vmcnt(0)" ::: "memory");               \
            });                                                                \
    }

#pragma unroll 1
    for (int t = 0; t < NT; t += 2) {
        G1_TILE(0, t);
        G1_TILE(1, t + 1);
    }
#undef G1_TILE
#undef G1_PHASE

    // Epilogue: relu(acc + bias) -> f16 store (same C/D mapping as before)
    const int orow = (lane >> 4) * 4;
    const int ocol = lane & 15;
#pragma unroll
    for (int n = 0; n < 4; ++n) {
        const long gn = blockN + wCol + n * 16 + ocol;
        const float bj = bias[gn];
#pragma unroll
        for (int m = 0; m < 8; ++m) {
#pragma unroll
            for (int r = 0; r < 4; ++r) {
                const float v = fmaxf(acc[m][n][r] + bj, 0.0f);
                outh[(size_t)(blockM + wRow + m * 16 + orow + r) * ND + gn] = (half_t)v;
            }
        }
    }
}

// ---------------------------------------------------------------------------
// GEMM2 fused: relu(h1 @ w2 + b2) @ w3, chunk-summed into cl_acc via
// device-scope atomics. h2 never materialized. f16x2 (W2 split kept).
// ---------------------------------------------------------------------------
__global__ __launch_bounds__(256, 3)
void gemm2_fused_kernel(const half_t* __restrict__ Ah,
                        const half_t* __restrict__ BTh, const half_t* __restrict__ BTl,
                        const float* __restrict__ bias, const float* __restrict__ w3,
                        float* __restrict__ cl_acc)
{
    constexpr int KD = H_, BK = 32;
    __shared__ __align__(16) half_t sAh[128 * BK];
    __shared__ __align__(16) half_t sBh[128 * BK];
    __shared__ __align__(16) half_t sBl[128 * BK];

    const int tid = threadIdx.x;
    const int lane = tid & 63;
    const int wave = tid >> 6;
    const int wm = (wave & 1) * 64;
    const int wn = (wave >> 1) * 64;
    const int d = blockIdx.y * 4 + blockIdx.x;
    const int xcd = d & 7;
    const int l = d >> 3;
    const int rowBlk = xcd * 16 + (l >> 2);
    const int colBlk = l & 3;
    const long blockM = (long)rowBlk * 128;
    const long blockN = (long)colBlk * 128;

    floatx4 acc[4][4];
#pragma unroll
    for (int i = 0; i < 4; ++i)
#pragma unroll
        for (int j = 0; j < 4; ++j) acc[i][j] = (floatx4){0.f, 0.f, 0.f, 0.f};

    const int srow = tid >> 2;
    const int skoff = (tid & 3) * 8;
    const int ldsoff = srow * BK + skoff;
    const int fr = lane & 15;
    const int fq = (lane >> 4) * 8;

    for (int k0 = 0; k0 < KD; k0 += BK) {
        __syncthreads();
#pragma unroll
        for (int p = 0; p < 2; ++p) {
            const int row = srow + p * 64;
            const size_t aoff = (size_t)(blockM + row) * KD + k0 + skoff;
            const size_t boff = (size_t)(blockN + row) * KD + k0 + skoff;
            const int loff = ldsoff + p * 2048;
            __builtin_amdgcn_global_load_lds(
                (const __attribute__((address_space(1))) void*)(Ah + aoff),
                (__attribute__((address_space(3))) void*)(sAh + loff), 16, 0, 0);
            __builtin_amdgcn_global_load_lds(
                (const __attribute__((address_space(1))) void*)(BTh + boff),
                (__attribute__((address_space(3))) void*)(sBh + loff), 16, 0, 0);
            __builtin_amdgcn_global_load_lds(
                (const __attribute__((address_space(1))) void*)(BTl + boff),
                (__attribute__((address_space(3))) void*)(sBl + loff), 16, 0, 0);
        }
        __syncthreads();

        half8v fbh[4], fbl[4];
#pragma unroll
        for (int t = 0; t < 4; ++t) {
            fbh[t] = *(const half8v*)(sBh + (wn + t * 16 + fr) * BK + fq);
            fbl[t] = *(const half8v*)(sBl + (wn + t * 16 + fr) * BK + fq);
        }
#pragma unroll
        for (int i = 0; i < 4; ++i) {
            const half8v fah = *(const half8v*)(sAh + (wm + i * 16 + fr) * BK + fq);
#pragma unroll
            for (int j = 0; j < 4; ++j) {
                acc[i][j] = __builtin_amdgcn_mfma_f32_16x16x32_f16(fah, fbh[j], acc[i][j], 0, 0, 0);
                acc[i][j] = __builtin_amdgcn_mfma_f32_16x16x32_f16(fah, fbl[j], acc[i][j], 0, 0, 0);
            }
        }
    }

    const int ocol = lane & 15;
    float p[E_];
#pragma unroll
    for (int e = 0; e < E_; ++e) p[e] = 0.0f;
#pragma unroll
    for (int j = 0; j < 4; ++j) {
        const int gn = (int)blockN + wn + j * 16 + ocol;
        const float bj = bias[gn];
        const float4 w3a = *(const float4*)(w3 + (size_t)gn * E_);
        const float4 w3b = *(const float4*)(w3 + (size_t)gn * E_ + 4);
        float colsum = 0.0f;
#pragma unroll
        for (int i = 0; i < 4; ++i)
#pragma unroll
            for (int r = 0; r < 4; ++r)
                colsum += fmaxf(acc[i][j][r] * OSCALE + bj, 0.0f);
        p[0] += colsum * w3a.x; p[1] += colsum * w3a.y;
        p[2] += colsum * w3a.z; p[3] += colsum * w3a.w;
        p[4] += colsum * w3b.x; p[5] += colsum * w3b.y;
        p[6] += colsum * w3b.z; p[7] += colsum * w3b.w;
    }
#pragma unroll
    for (int e = 0; e < E_; ++e)
#pragma unroll
        for (int off = 32; off > 0; off >>= 1)
            p[e] += __shfl_xor(p[e], off);
#pragma unroll
    for (int e = 0; e < E_; ++e)
        if (lane == e) atomicAdd(&cl_acc[rowBlk * E_ + e], p[e]);
}

// ---------------------------------------------------------------------------
// Final+route (one launch, 64 blocks): every block redundantly computes the
// chunk logits, argmax, and hysteresis scan, then writes its routing-weight
// slice. Block 0 additionally writes EI/CL/stats.
// prev_expert_indices is dead in the reference (scan init zeros + is_first).
// ---------------------------------------------------------------------------
__global__ __launch_bounds__(256)
void final_route_kernel(const float* __restrict__ cl_acc, const float* __restrict__ b3,
                        float* __restrict__ out)
{
    __shared__ float cl[B_ * C_][E_];
    __shared__ int tops[B_ * C_];
    __shared__ int finals[B_ * C_];
    __shared__ int flips[B_];
    __shared__ float ent[B_ * C_];

    const int tid = threadIdx.x;

    if (tid < B_ * C_) {
        int best = 0;
        float bvv = -1e30f;
#pragma unroll
        for (int e = 0; e < E_; ++e) {
            const float v = cl_acc[tid * E_ + e] * (1.0f / CHUNK_) + b3[e];
            cl[tid][e] = v;
            if (v > bvv) { bvv = v; best = e; }   // first-max tiebreak == np.argmax
        }
        tops[tid] = best;
    }
    __syncthreads();

    if (tid < B_) {
        const int b = tid;
        int prev = 0, fl = 0;
        for (int c = 0; c < C_; ++c) {
            const int t = tops[b * C_ + c];
            int fin;
            if (c == 0) {
                fin = t;
            } else {
                const float cur = cl[b * C_ + c][t];
                const float pv = cl[b * C_ + c][prev];
                const bool sw = (cur - pv) > TAU_;
                if (sw) fl++;
                fin = sw ? t : prev;
            }
            finals[b * C_ + c] = fin;
            prev = fin;
        }
        flips[b] = fl;
    }
    __syncthreads();

    {
        const int tok = blockIdx.x * 256 + tid;
        const int b = tok >> 12;
        const int c = (tok & (S_ - 1)) >> 7;
        const int e = finals[b * C_ + c];
        float4 v0 = make_float4(e == 0 ? 1.f : 0.f, e == 1 ? 1.f : 0.f,
                                e == 2 ? 1.f : 0.f, e == 3 ? 1.f : 0.f);
        float4 v1 = make_float4(e == 4 ? 1.f : 0.f, e == 5 ? 1.f : 0.f,
                                e == 6 ? 1.f : 0.f, e == 7 ? 1.f : 0.f);
        float4* dst = (float4*)(out + OUT_RW + (size_t)tok * E_);
        dst[0] = v0;
        dst[1] = v1;
    }

    if (blockIdx.x == 0) {
        if (tid < B_ * C_) {
            out[OUT_EI + tid] = (float)finals[tid];
#pragma unroll
            for (int e = 0; e < E_; ++e) out[OUT_CL + tid * E_ + e] = cl[tid][e];
            float m = cl[tid][0];
            for (int e = 1; e < E_; ++e) m = fmaxf(m, cl[tid][e]);
            float pr[E_], s = 0.0f;
            for (int e = 0; e < E_; ++e) { pr[e] = expf(cl[tid][e] - m); s += pr[e]; }
            const float inv = 1.0f / s;
            float h = 0.0f;
            for (int e = 0; e < E_; ++e) { const float pe = pr[e] * inv; h -= pe * logf(pe + 1e-8f); }
            ent[tid] = h;
        }
        __syncthreads();
        if (tid == 0) {
            float esum = 0.0f;
            for (int i = 0; i < B_ * C_; ++i) esum += ent[i];
            out[OUT_GE] = esum / (float)(B_ * C_);

            int cnt[E_];
            for (int e = 0; e < E_; ++e) cnt[e] = 0;
            for (int i = 0; i < B_ * C_; ++i) cnt[finals[i]]++;
            float n2 = 0.0f;
            for (int e = 0; e < E_; ++e) {
                const float u = (float)cnt[e] / (float)(B_ * C_);
                out[OUT_UT + e] = u;
                n2 += u * u;
            }
            const int totfl = flips[0] + flips[1] + flips[2] + flips[3];
            out[OUT_FR] = (float)totfl / (float)(B_ * (C_ - 1));
            out[OUT_RC] = sqrtf(n2);
        }
    }
}

// ---------------------------------------------------------------------------
extern "C" void kernel_launch(void* const* d_in, const int* in_sizes, int n_in,
                              void* d_out, int out_size, void* d_ws, size_t ws_size,
                              hipStream_t stream)
{
    const float* x  = (const float*)d_in[0];
    const float* w1 = (const float*)d_in[2];
    const float* b1 = (const float*)d_in[3];
    const float* w2 = (const float*)d_in[4];
    const float* b2 = (const float*)d_in[5];
    const float* w3 = (const float*)d_in[6];
    const float* b3 = (const float*)d_in[7];
    float* out = (float*)d_out;

    half_t* xh   = (half_t*)d_ws;                    // 64 MB
    half_t* w1t  = xh + (size_t)M_ * D_;             // 4 MB
    half_t* h1h  = w1t + (size_t)H_ * D_;            // 32 MB
    half_t* w2th = h1h + (size_t)M_ * H_;            // 1 MB
    half_t* w2tl = w2th + (size_t)H2_ * H_;          // 1 MB
    float*  cl_acc = (float*)(w2tl + (size_t)H2_ * H_);  // 4 KB

    // 1) prep: x->f16 convert + transposes + cl_acc zero (one launch)
    prep_kernel<<<dim3(10753), dim3(256), 0, stream>>>(x, w1, w2, xh, w1t, w2th, w2tl, cl_acc);
    // 2) GEMM1: 256x256 8-phase counted-vmcnt schedule, 256 blocks (1/CU)
    gemm1_kernel<<<dim3(256), dim3(512), 0, stream>>>(xh, w1t, b1, h1h);
    // 3) GEMM2 fused through layer-3 + chunk-sum
    gemm2_fused_kernel<<<dim3(H2_ / 128, M_ / 128), dim3(256), 0, stream>>>(
        h1h, w2th, w2tl, b2, w3, cl_acc);
    // 4) finalize + routing weights (one launch)
    final_route_kernel<<<dim3(M_ / 256), dim3(256), 0, stream>>>(cl_acc, b3, out);
}

// Round 6
// 323.121 us; speedup vs baseline: 1.1464x; 1.0599x over previous
//
#include <hip/hip_runtime.h>
#include <math.h>

typedef _Float16 half_t;
typedef __attribute__((ext_vector_type(4))) _Float16 half4v;
typedef __attribute__((ext_vector_type(8))) _Float16 half8v;
typedef __attribute__((ext_vector_type(4))) float floatx4;

constexpr int B_ = 4, S_ = 4096, D_ = 2048, H_ = 1024, H2_ = 512, E_ = 8;
constexpr int CHUNK_ = 128;
constexpr int C_ = S_ / CHUNK_;          // 32
constexpr int M_ = B_ * S_;              // 16384
constexpr float TAU_ = 0.7f;
// Precision ledger (measured): full split absmax=0; x/W1 pure-f16 + W2 split
// -> absmax = 2^-9, 60x under threshold. R12 drops the W2 lo-residual:
// estimated delta-logit ~1e-4 (f16 eps * ||w2||*||h1||*sqrt(K) through w3),
// coherent across the chunk mean but ~20x below the current 2^-9 absmax.
// CANARY: if absmax > ~0.01 this was wrong -> restore the split.

constexpr int OUT_RW = 0;
constexpr int OUT_EI = OUT_RW + B_ * S_ * E_;
constexpr int OUT_CL = OUT_EI + B_ * C_;
constexpr int OUT_GE = OUT_CL + B_ * C_ * E_;
constexpr int OUT_UT = OUT_GE + 1;
constexpr int OUT_FR = OUT_UT + E_;
constexpr int OUT_RC = OUT_FR + 1;

// ---------------------------------------------------------------------------
// Prep (one launch):
//   blocks [0,8192):       x fp32 -> f16 (512 half8 per block, 16B stores)
//   blocks [8192,10240):   w1 [D,H] -> w1t [H,D] f16
//   blocks [10240,10752):  w2 [H,H2] -> w2t [H2,H] f16 (hi only, unscaled)
//   block  10752:          zero cl_acc
// ---------------------------------------------------------------------------
__global__ __launch_bounds__(256)
void prep_kernel(const float* __restrict__ x, const float* __restrict__ w1,
                 const float* __restrict__ w2,
                 half_t* __restrict__ xh, half_t* __restrict__ w1t,
                 half_t* __restrict__ w2th,
                 float* __restrict__ cl_acc)
{
    __shared__ float tile[32][33];
    const int tx = threadIdx.x & 31;
    const int ty = threadIdx.x >> 5;
    const int bid = blockIdx.x;

    if (bid < 8192) {                     // convert x: 16B/lane stores
        const int base = bid * 512 + threadIdx.x;   // half8 index space
#pragma unroll
        for (int p = 0; p < 2; ++p) {
            const int j = base + p * 256;
            const float4 a = ((const float4*)x)[2 * j];
            const float4 b = ((const float4*)x)[2 * j + 1];
            half8v h;
            h[0] = (half_t)a.x; h[1] = (half_t)a.y;
            h[2] = (half_t)a.z; h[3] = (half_t)a.w;
            h[4] = (half_t)b.x; h[5] = (half_t)b.y;
            h[6] = (half_t)b.z; h[7] = (half_t)b.w;
            ((half8v*)xh)[j] = h;
        }
    } else if (bid < 10240) {             // w1 transpose -> f16
        const int b2 = bid - 8192;
        const int n0 = (b2 & 31) * 32;    // H_/32 = 32
        const int k0 = (b2 >> 5) * 32;    // D_/32 = 64
#pragma unroll
        for (int r = 0; r < 4; ++r)
            tile[ty + r * 8][tx] = w1[(size_t)(k0 + ty + r * 8) * H_ + n0 + tx];
        __syncthreads();
#pragma unroll
        for (int r = 0; r < 4; ++r)
            w1t[(size_t)(n0 + ty + r * 8) * D_ + k0 + tx] = (half_t)tile[tx][ty + r * 8];
    } else if (bid < 10752) {             // w2 transpose -> f16 (hi only)
        const int b2 = bid - 10240;
        const int n0 = (b2 & 15) * 32;    // H2_/32 = 16
        const int k0 = (b2 >> 4) * 32;    // H_/32 = 32
#pragma unroll
        for (int r = 0; r < 4; ++r)
            tile[ty + r * 8][tx] = w2[(size_t)(k0 + ty + r * 8) * H2_ + n0 + tx];
        __syncthreads();
#pragma unroll
        for (int r = 0; r < 4; ++r)
            w2th[(size_t)(n0 + ty + r * 8) * H_ + k0 + tx] = (half_t)tile[tx][ty + r * 8];
    } else {                              // zero chunk-logit accumulator
        for (int i = threadIdx.x; i < B_ * C_ * E_; i += 256) cl_acc[i] = 0.0f;
    }
}

// ---------------------------------------------------------------------------
// GEMM1: h1 = relu(xh @ w1 + b1) -> f16.
// R7: 256x256x(BK=64) 8-phase counted-vmcnt schedule (learn_hip m201 port).
// R8: paired-row LDS layout -> bank conflicts = 0 (verified by PMC).
// R9/R10/R11 (all REVERTED, measured neutral-or-worse): reg-dbuf, read pins,
//   unroll 1. Main loop is frozen at the R8 form (best measured: 83.4 us).
// R12: epilogue LDS-transpose. WRITE_SIZE was 61 MB vs 32 ideal (2B scatter
//   -> partial sectors). Stage C half-tile (128x256 f16) in the now-dead
//   smem with XOR slot swizzle (write quarters hit disjoint bank groups;
//   reads stream full rows), then 16B coalesced stores.
// ---------------------------------------------------------------------------
__device__ __forceinline__ int lds_off_g(int row, int q)
{
    // half-index into a k-half tile for (row, k-quarter q)
    const int line = row >> 1;
    const int sl = (((row & 1) << 2) | q) ^ (line & 7);
    return line * 64 + sl * 8;
}

__device__ __forceinline__ void stage_half_g1(const half_t* __restrict__ g,
                                              half_t* l, int tid)
{
    // LDS[line][s] <- global(row = 2*line + p, k = q*8) with p*4+q = s^(line&7)
    const int s = tid & 7;
#pragma unroll
    for (int r = 0; r < 2; ++r) {
        const int line = r * 64 + (tid >> 3);
        const int u = s ^ (line & 7);
        const int row = line * 2 + (u >> 2);
        const int kq = (u & 3) * 8;
        __builtin_amdgcn_global_load_lds(
            (const __attribute__((address_space(1))) void*)(g + (size_t)row * D_ + kq),
            (__attribute__((address_space(3))) void*)(l + (r * 512 + tid) * 8),
            16, 0, 0);
    }
}

__global__ __launch_bounds__(512, 2)
void gemm1_kernel(const half_t* __restrict__ Ah,
                  const half_t* __restrict__ BTh,
                  const float* __restrict__ bias, half_t* __restrict__ outh)
{
    constexpr int KD = D_;        // 2048
    constexpr int ND = H_;        // 1024
    constexpr int NT = KD / 64;   // 32 K-tiles

    // Single 128 KB pool: main loop uses [dbuf][khalf] A/B half-tiles;
    // epilogue reuses the front 64 KB as the C staging buffer.
    __shared__ __align__(16) half_t smem[65536];
#define SA(BUF, H) (smem + ((BUF) * 2 + (H)) * 8192)
#define SB(BUF, H) (smem + 32768 + ((BUF) * 2 + (H)) * 8192)

    const int tid = threadIdx.x;
    const int lane = tid & 63;
    const int wave = tid >> 6;
    const int wRow = (wave >> 2) * 128;     // 2 M-wave-groups
    const int wCol = (wave & 3) * 64;       // 4 N-wave-groups
    const int fr = lane & 15;
    const int q = lane >> 4;                // k-quarter

    // XCD-bijective swizzle: bid%8 = XCD; each XCD owns a contiguous
    // 8-M-block stripe x all 4 N-blocks (B panels + A rows L2-local).
    const int bid = blockIdx.x;
    const long blockM = (long)((bid & 7) * 8 + (bid >> 5)) * 256;
    const long blockN = (long)((bid >> 3) & 3) * 256;

    const half_t* gA = Ah + (size_t)blockM * KD;
    const half_t* gB = BTh + (size_t)blockN * KD;

    floatx4 acc[8][4];
#pragma unroll
    for (int i = 0; i < 8; ++i)
#pragma unroll
        for (int j = 0; j < 4; ++j) acc[i][j] = (floatx4){0.f, 0.f, 0.f, 0.f};

    // Prologue: tile0 complete + steady-state 3 halves of tile1 in flight.
    stage_half_g1(gA,      SA(0, 0), tid);   // A0.h0
    stage_half_g1(gB,      SB(0, 0), tid);   // B0.h0
    stage_half_g1(gA + 32, SA(0, 1), tid);   // A0.h1
    stage_half_g1(gB + 32, SB(0, 1), tid);   // B0.h1
    stage_half_g1(gB + 64, SB(1, 0), tid);   // B1.h0   (as-if (t-1,P2))
    stage_half_g1(gA + 64, SA(1, 0), tid);   // A1.h0   (as-if (t-1,P3))
    stage_half_g1(gB + 96, SB(1, 1), tid);   // B1.h1   (as-if (t-1,P4))
    asm volatile("s_waitcnt vmcnt(6)" ::: "memory");   // tile0 landed
    __builtin_amdgcn_s_barrier();
    __builtin_amdgcn_sched_barrier(0);

    half8v bfr[4];

#define G1_PHASE(BUF, H, MB, STAGE_STMT, TAIL_STMT)                            \
    {                                                                          \
        half8v afr[4];                                                         \
        if ((MB) == 0) {                                                       \
            _Pragma("unroll")                                                  \
            for (int n = 0; n < 4; ++n)                                        \
                bfr[n] = *(const half8v*)(SB(BUF, H) +                         \
                          lds_off_g(wCol + n * 16 + fr, q));                   \
        }                                                                      \
        _Pragma("unroll")                                                      \
        for (int m = 0; m < 4; ++m)                                            \
            afr[m] = *(const half8v*)(SA(BUF, H) +                             \
                      lds_off_g(wRow + (MB) + m * 16 + fr, q));                \
        STAGE_STMT;                                                            \
        __builtin_amdgcn_s_barrier();                                          \
        asm volatile("s_waitcnt lgkmcnt(0)" ::: "memory");                     \
        __builtin_amdgcn_sched_barrier(0);                                     \
        __builtin_amdgcn_s_setprio(1);                                         \
        _Pragma("unroll")                                                      \
        for (int m = 0; m < 4; ++m)                                            \
            _Pragma("unroll")                                                  \
            for (int n = 0; n < 4; ++n)                                        \
                acc[(MB) / 16 + m][n] = __builtin_amdgcn_mfma_f32_16x16x32_f16(\
                    afr[m], bfr[n], acc[(MB) / 16 + m][n], 0, 0, 0);           \
        __builtin_amdgcn_s_setprio(0);                                         \
        TAIL_STMT;                                                             \
        __builtin_amdgcn_s_barrier();                                          \
        __builtin_amdgcn_sched_barrier(0);                                     \
    }

#define G1_TILE(BUF, T)                                                        \
    {                                                                          \
        G1_PHASE(BUF, 0, 0,                                                    \
            if ((T) + 1 < NT)                                                  \
                stage_half_g1(gA + ((T) + 1) * 64 + 32, SA((BUF) ^ 1, 1), tid),\
            );                                                                 \
        G1_PHASE(BUF, 0, 64,                                                   \
            if ((T) + 2 < NT)                                                  \
                stage_half_g1(gB + ((T) + 2) * 64, SB(BUF, 0), tid),           \
            );                                                                 \
        G1_PHASE(BUF, 1, 0,                                                    \
            if ((T) + 2 < NT)                                                  \
                stage_half_g1(gA + ((T) + 2) * 64, SA(BUF, 0), tid),           \
            );                                                                 \
        G1_PHASE(BUF, 1, 64,                                                   \
            if ((T) + 2 < NT)                                                  \
                stage_half_g1(gB + ((T) + 2) * 64 + 32, SB(BUF, 1), tid),      \
            if ((T) < NT - 2) {                                                \
                asm volatile("s_waitcnt vmcnt(6)" ::: "memory");               \
            } else if ((T) == NT - 2) {                                        \
                asm volatile("s_waitcnt vmcnt(0)" ::: "memory");               \
            });                                                                \
    }

    for (int t = 0; t < NT; t += 2) {
        G1_TILE(0, t);
        G1_TILE(1, t + 1);
    }
#undef G1_TILE
#undef G1_PHASE

    // Epilogue R12: stage C half-tile in LDS (XOR slot swizzle), then
    // coalesced 16B row-streaming stores. Waves 0-3 own rows 0-127 (h=0),
    // waves 4-7 own rows 128-255 (h=1).
    const int orow = (lane >> 4) * 4;
    const int ocol = lane & 15;
    half_t* sC = smem;    // 32768 halves = 128 rows x 32 slots x 8 halves
#pragma unroll 1
    for (int h = 0; h < 2; ++h) {
        if ((wRow >> 7) == h) {
#pragma unroll
            for (int n = 0; n < 4; ++n) {
                const int col = wCol + n * 16 + ocol;
                const float bj = bias[blockN + col];
#pragma unroll
                for (int m = 0; m < 8; ++m) {
#pragma unroll
                    for (int r = 0; r < 4; ++r) {
                        const int lrow = m * 16 + orow + r;
                        const int slot = (col >> 3) ^ (((lrow >> 2) & 3) << 3);
                        sC[lrow * 256 + slot * 8 + (col & 7)] =
                            (half_t)fmaxf(acc[m][n][r] + bj, 0.0f);
                    }
                }
            }
        }
        asm volatile("s_waitcnt lgkmcnt(0)" ::: "memory");
        __builtin_amdgcn_s_barrier();
#pragma unroll
        for (int i = 0; i < 8; ++i) {
            const int g = i * 512 + tid;
            const int row = g >> 5;
            const int sl = g & 31;
            const half8v v = *(const half8v*)(
                sC + row * 256 + ((sl ^ (((row >> 2) & 3) << 3)) << 3));
            *(half8v*)(outh + (size_t)(blockM + h * 128 + row) * ND + blockN + sl * 8) = v;
        }
        __builtin_amdgcn_s_barrier();
    }
#undef SA
#undef SB
}

// ---------------------------------------------------------------------------
// GEMM2 fused: relu(h1 @ w2 + b2) @ w3, chunk-summed into cl_acc via
// device-scope atomics. h2 never materialized. R12: W2 hi-only (lo-residual
// dropped; halves MFMA work, removes the third staging stream).
// ---------------------------------------------------------------------------
__global__ __launch_bounds__(256, 3)
void gemm2_fused_kernel(const half_t* __restrict__ Ah,
                        const half_t* __restrict__ BTh,
                        const float* __restrict__ bias, const float* __restrict__ w3,
                        float* __restrict__ cl_acc)
{
    constexpr int KD = H_, BK = 32;
    __shared__ __align__(16) half_t sAh[128 * BK];
    __shared__ __align__(16) half_t sBh[128 * BK];

    const int tid = threadIdx.x;
    const int lane = tid & 63;
    const int wave = tid >> 6;
    const int wm = (wave & 1) * 64;
    const int wn = (wave >> 1) * 64;
    const int d = blockIdx.y * 4 + blockIdx.x;
    const int xcd = d & 7;
    const int l = d >> 3;
    const int rowBlk = xcd * 16 + (l >> 2);
    const int colBlk = l & 3;
    const long blockM = (long)rowBlk * 128;
    const long blockN = (long)colBlk * 128;

    floatx4 acc[4][4];
#pragma unroll
    for (int i = 0; i < 4; ++i)
#pragma unroll
        for (int j = 0; j < 4; ++j) acc[i][j] = (floatx4){0.f, 0.f, 0.f, 0.f};

    const int srow = tid >> 2;
    const int skoff = (tid & 3) * 8;
    const int ldsoff = srow * BK + skoff;
    const int fr = lane & 15;
    const int fq = (lane >> 4) * 8;

    for (int k0 = 0; k0 < KD; k0 += BK) {
        __syncthreads();
#pragma unroll
        for (int p = 0; p < 2; ++p) {
            const int row = srow + p * 64;
            const size_t aoff = (size_t)(blockM + row) * KD + k0 + skoff;
            const size_t boff = (size_t)(blockN + row) * KD + k0 + skoff;
            const int loff = ldsoff + p * 2048;
            __builtin_amdgcn_global_load_lds(
                (const __attribute__((address_space(1))) void*)(Ah + aoff),
                (__attribute__((address_space(3))) void*)(sAh + loff), 16, 0, 0);
            __builtin_amdgcn_global_load_lds(
                (const __attribute__((address_space(1))) void*)(BTh + boff),
                (__attribute__((address_space(3))) void*)(sBh + loff), 16, 0, 0);
        }
        __syncthreads();

        half8v fbh[4];
#pragma unroll
        for (int t = 0; t < 4; ++t)
            fbh[t] = *(const half8v*)(sBh + (wn + t * 16 + fr) * BK + fq);
#pragma unroll
        for (int i = 0; i < 4; ++i) {
            const half8v fah = *(const half8v*)(sAh + (wm + i * 16 + fr) * BK + fq);
#pragma unroll
            for (int j = 0; j < 4; ++j)
                acc[i][j] = __builtin_amdgcn_mfma_f32_16x16x32_f16(fah, fbh[j], acc[i][j], 0, 0, 0);
        }
    }

    const int ocol = lane & 15;
    float p[E_];
#pragma unroll
    for (int e = 0; e < E_; ++e) p[e] = 0.0f;
#pragma unroll
    for (int j = 0; j < 4; ++j) {
        const int gn = (int)blockN + wn + j * 16 + ocol;
        const float bj = bias[gn];
        const float4 w3a = *(const float4*)(w3 + (size_t)gn * E_);
        const float4 w3b = *(const float4*)(w3 + (size_t)gn * E_ + 4);
        float colsum = 0.0f;
#pragma unroll
        for (int i = 0; i < 4; ++i)
#pragma unroll
            for (int r = 0; r < 4; ++r)
                colsum += fmaxf(acc[i][j][r] + bj, 0.0f);
        p[0] += colsum * w3a.x; p[1] += colsum * w3a.y;
        p[2] += colsum * w3a.z; p[3] += colsum * w3a.w;
        p[4] += colsum * w3b.x; p[5] += colsum * w3b.y;
        p[6] += colsum * w3b.z; p[7] += colsum * w3b.w;
    }
#pragma unroll
    for (int e = 0; e < E_; ++e)
#pragma unroll
        for (int off = 32; off > 0; off >>= 1)
            p[e] += __shfl_xor(p[e], off);
#pragma unroll
    for (int e = 0; e < E_; ++e)
        if (lane == e) atomicAdd(&cl_acc[rowBlk * E_ + e], p[e]);
}

// ---------------------------------------------------------------------------
// Final+route (one launch, 64 blocks): every block redundantly computes the
// chunk logits, argmax, and hysteresis scan, then writes its routing-weight
// slice. Block 0 additionally writes EI/CL/stats.
// prev_expert_indices is dead in the reference (scan init zeros + is_first).
// ---------------------------------------------------------------------------
__global__ __launch_bounds__(256)
void final_route_kernel(const float* __restrict__ cl_acc, const float* __restrict__ b3,
                        float* __restrict__ out)
{
    __shared__ float cl[B_ * C_][E_];
    __shared__ int tops[B_ * C_];
    __shared__ int finals[B_ * C_];
    __shared__ int flips[B_];
    __shared__ float ent[B_ * C_];

    const int tid = threadIdx.x;

    if (tid < B_ * C_) {
        int best = 0;
        float bvv = -1e30f;
#pragma unroll
        for (int e = 0; e < E_; ++e) {
            const float v = cl_acc[tid * E_ + e] * (1.0f / CHUNK_) + b3[e];
            cl[tid][e] = v;
            if (v > bvv) { bvv = v; best = e; }   // first-max tiebreak == np.argmax
        }
        tops[tid] = best;
    }
    __syncthreads();

    if (tid < B_) {
        const int b = tid;
        int prev = 0, fl = 0;
        for (int c = 0; c < C_; ++c) {
            const int t = tops[b * C_ + c];
            int fin;
            if (c == 0) {
                fin = t;
            } else {
                const float cur = cl[b * C_ + c][t];
                const float pv = cl[b * C_ + c][prev];
                const bool sw = (cur - pv) > TAU_;
                if (sw) fl++;
                fin = sw ? t : prev;
            }
            finals[b * C_ + c] = fin;
            prev = fin;
        }
        flips[b] = fl;
    }
    __syncthreads();

    {
        const int tok = blockIdx.x * 256 + tid;
        const int b = tok >> 12;
        const int c = (tok & (S_ - 1)) >> 7;
        const int e = finals[b * C_ + c];
        float4 v0 = make_float4(e == 0 ? 1.f : 0.f, e == 1 ? 1.f : 0.f,
                                e == 2 ? 1.f : 0.f, e == 3 ? 1.f : 0.f);
        float4 v1 = make_float4(e == 4 ? 1.f : 0.f, e == 5 ? 1.f : 0.f,
                                e == 6 ? 1.f : 0.f, e == 7 ? 1.f : 0.f);
        float4* dst = (float4*)(out + OUT_RW + (size_t)tok * E_);
        dst[0] = v0;
        dst[1] = v1;
    }

    if (blockIdx.x == 0) {
        if (tid < B_ * C_) {
            out[OUT_EI + tid] = (float)finals[tid];
#pragma unroll
            for (int e = 0; e < E_; ++e) out[OUT_CL + tid * E_ + e] = cl[tid][e];
            float m = cl[tid][0];
            for (int e = 1; e < E_; ++e) m = fmaxf(m, cl[tid][e]);
            float pr[E_], s = 0.0f;
            for (int e = 0; e < E_; ++e) { pr[e] = expf(cl[tid][e] - m); s += pr[e]; }
            const float inv = 1.0f / s;
            float h = 0.0f;
            for (int e = 0; e < E_; ++e) { const float pe = pr[e] * inv; h -= pe * logf(pe + 1e-8f); }
            ent[tid] = h;
        }
        __syncthreads();
        if (tid == 0) {
            float esum = 0.0f;
            for (int i = 0; i < B_ * C_; ++i) esum += ent[i];
            out[OUT_GE] = esum / (float)(B_ * C_);

            int cnt[E_];
            for (int e = 0; e < E_; ++e) cnt[e] = 0;
            for (int i = 0; i < B_ * C_; ++i) cnt[finals[i]]++;
            float n2 = 0.0f;
            for (int e = 0; e < E_; ++e) {
                const float u = (float)cnt[e] / (float)(B_ * C_);
                out[OUT_UT + e] = u;
                n2 += u * u;
            }
            const int totfl = flips[0] + flips[1] + flips[2] + flips[3];
            out[OUT_FR] = (float)totfl / (float)(B_ * (C_ - 1));
            out[OUT_RC] = sqrtf(n2);
        }
    }
}

// ---------------------------------------------------------------------------
extern "C" void kernel_launch(void* const* d_in, const int* in_sizes, int n_in,
                              void* d_out, int out_size, void* d_ws, size_t ws_size,
                              hipStream_t stream)
{
    const float* x  = (const float*)d_in[0];
    const float* w1 = (const float*)d_in[2];
    const float* b1 = (const float*)d_in[3];
    const float* w2 = (const float*)d_in[4];
    const float* b2 = (const float*)d_in[5];
    const float* w3 = (const float*)d_in[6];
    const float* b3 = (const float*)d_in[7];
    float* out = (float*)d_out;

    half_t* xh   = (half_t*)d_ws;                    // 64 MB
    half_t* w1t  = xh + (size_t)M_ * D_;             // 4 MB
    half_t* h1h  = w1t + (size_t)H_ * D_;            // 32 MB
    half_t* w2th = h1h + (size_t)M_ * H_;            // 1 MB
    half_t* w2tl = w2th + (size_t)H2_ * H_;          // 1 MB (unused, layout kept)
    float*  cl_acc = (float*)(w2tl + (size_t)H2_ * H_);  // 4 KB

    // 1) prep: x->f16 convert + transposes + cl_acc zero (one launch)
    prep_kernel<<<dim3(10753), dim3(256), 0, stream>>>(x, w1, w2, xh, w1t, w2th, cl_acc);
    // 2) GEMM1: 256x256 counted-vmcnt schedule, 256 blocks (1/CU)
    gemm1_kernel<<<dim3(256), dim3(512), 0, stream>>>(xh, w1t, b1, h1h);
    // 3) GEMM2 fused through layer-3 + chunk-sum (W2 hi-only)
    gemm2_fused_kernel<<<dim3(H2_ / 128, M_ / 128), dim3(256), 0, stream>>>(
        h1h, w2th, b2, w3, cl_acc);
    // 4) finalize + routing weights (one launch)
    final_route_kernel<<<dim3(M_ / 256), dim3(256), 0, stream>>>(cl_acc, b3, out);
}